// Round 1
// baseline (307.132 us; speedup 1.0000x reference)
//
#include <hip/hip_runtime.h>
#include <cstdint>
#include <cstddef>

typedef unsigned short u16;
typedef __attribute__((ext_vector_type(8))) short short8;
typedef __attribute__((ext_vector_type(8))) u16 ushort8;
typedef __attribute__((ext_vector_type(4))) float float4_t;

#define BB 8
#define NN 8192
#define DD 64
#define NTILES 64            // 8192 / 128 column tiles (pre_kernel format)
#define TILE_SHORTS 8192     // 128 points * 64 k (bf16)
#define LDS_STRIDE 68        // 64 floats + 4 pad (bank spread)

__device__ inline u16 f32_to_bf16(float f) {
  unsigned u = __float_as_uint(f);
  u += 0x7FFFu + ((u >> 16) & 1u);   // RNE
  return (u16)(u >> 16);
}

__device__ inline unsigned enc_ord(float f) {
  unsigned u = __float_as_uint(f);
  return (u & 0x80000000u) ? ~u : (u | 0x80000000u);
}
__device__ inline float dec_ord(unsigned u) {
  return __uint_as_float((u & 0x80000000u) ? (u & 0x7fffffffu) : ~u);
}

// ---------------------------------------------------------------------------
// K1: one block = one 128x64 tile. Coalesced read-once -> LDS -> swizzled
// bf16 tile (MFMA fragment chunk order) + 0.5*|row|^2. Zeroes out[] and, in
// the fallback path, the ordered-uint max buffers.  [verified R6/R7 — UNCHANGED]
// Chunk layout per tile: [I(8)][s(2)] chunks of 1KB; within a chunk lane
// l (l=qq*16+rl) holds point I*16+rl, k = s*32+qq*8+j (j=0..7, 16B).
// ---------------------------------------------------------------------------
__global__ __launch_bounds__(256) void pre_kernel(
    const float* __restrict__ x, const float* __restrict__ y,
    u16* __restrict__ xs, u16* __restrict__ ys,
    float* __restrict__ x2h, float* __restrict__ y2h,
    unsigned* __restrict__ rowmax_u, unsigned* __restrict__ colmax_u,
    float* __restrict__ out, const int use_part)
{
  __shared__ float stage[128 * LDS_STRIDE];   // 34 KB

  const int bid = blockIdx.x;          // 1024: 0..511 -> x, 512..1023 -> y
  const int tid = threadIdx.x;

  if (!use_part) {
    if (bid < 256)      colmax_u[(bid << 8) | tid] = 0u;
    else if (bid < 512) rowmax_u[((bid - 256) << 8) | tid] = 0u;
  }
  if (bid == 0 && tid == 0) out[0] = 0.f;

  const bool isY = bid >= 512;
  const int t = bid & 511;             // tile id = b*64 + nt
  const float* src = (isY ? y : x) + (size_t)t * (128 * DD);
  u16* dst = (isY ? ys : xs) + (size_t)t * TILE_SHORTS;
  float* s2 = (isY ? y2h : x2h) + t * 128;

#pragma unroll
  for (int c = 0; c < 8; ++c) {
    const int idx = c * 256 + tid;     // float4 index within tile (0..2047)
    float4 f = ((const float4*)src)[idx];
    const int r = idx >> 4, kc = idx & 15;
    *(float4*)&stage[r * LDS_STRIDE + kc * 4] = f;
  }
  __syncthreads();

  {
    const int r = tid >> 1, half = tid & 1;
    const float* rp = &stage[r * LDS_STRIDE + half * 32];
    float ss = 0.f;
#pragma unroll
    for (int k = 0; k < 8; ++k) {
      float4 f = *(const float4*)&rp[k * 4];
      ss += f.x*f.x + f.y*f.y + f.z*f.z + f.w*f.w;
    }
    ss += __shfl_xor(ss, 1);
    if (half == 0) s2[r] = 0.5f * ss;
  }

  {
    const int w = tid >> 6, lane = tid & 63;
    const int qq = lane >> 4, rl = lane & 15;
#pragma unroll
    for (int u = 0; u < 4; ++u) {
      const int chunk = w * 4 + u;
      const int I = chunk >> 1, s = chunk & 1;
      const float* rp = &stage[(I*16 + rl) * LDS_STRIDE + s*32 + qq*8];
      ushort8 o;
#pragma unroll
      for (int j = 0; j < 8; ++j) o[j] = f32_to_bf16(rp[j]);
      *(ushort8*)(dst + chunk*512 + lane*8) = o;
    }
  }
}

// ---------------------------------------------------------------------------
// K2: main — R9 restructure for OCCUPANCY. The R3 inner math is verbatim
// (acc = xy - x2/2 via C-init, j-sequential acc — R4/R6/R8 bans respected),
// but each block now owns a 64-ROW tile (half a pre_kernel 128-tile):
//   grid 2048 = h(1b) | nt(7b) | b(3b)   (b in low bits: XCD affinity)
// Per-wave pinned state halves (afr 32, negx2 16, rowmax 16, acc 16) so the
// whole kernel fits ~135 regs -> 3 waves/SIMD under launch_bounds(256,3)
// (was ~184 V+A regs -> 2 waves/SIMD, Occupancy 18.8%, MfmaUtil 33%).
// Also: tail-peeled 2x-unrolled A/B buffer rotation (no copies), pure
// pointer-bump addressing (no cndmask clamp / per-iter 64-bit rebuilds),
// max3-shaped col trees.
// ---------------------------------------------------------------------------
__global__ __launch_bounds__(256, 3) void main_kernel(
    const u16* __restrict__ xs, const u16* __restrict__ ys,
    const float* __restrict__ x2h, const float* __restrict__ y2h,
    float* __restrict__ rowpart, float* __restrict__ colpart,
    unsigned* __restrict__ rowmax_u, unsigned* __restrict__ colmax_u,
    const int use_part)
{
  __shared__ float rowbuf[4][64];

  const int bid = blockIdx.x;            // 2048
  const int b   = bid & 7;               // XCD-affine
  const int nt  = (bid >> 3) & 127;      // 64-row tile id
  const int h   = bid >> 10;             // 0..1 column half
  const int tid = threadIdx.x;
  const int w = tid >> 6, lane = tid & 63;   // w = column-slice owner
  const int l15 = lane & 15, q = lane >> 4;
  const int n0 = nt << 6;
  const int mt_start = h << 5;           // 32 col-tiles per block

  // ---- A fragments: 64 rows (half of a 128-row xs tile), both K-halves ----
  const u16* xs_tile = xs + (size_t)((b << 6) | (nt >> 1)) * TILE_SHORTS
                       + (nt & 1) * 4096;          // 4 chunks * 1024 shorts
  short8 afr[4][2];
#pragma unroll
  for (int i = 0; i < 4; ++i)
#pragma unroll
    for (int s = 0; s < 2; ++s)
      afr[i][s] = *(const short8*)(xs_tile + (i*2 + s)*512 + lane*8);

  // ---- C-init quads: -x2/2 per row (fp32 exact) ----
  float4_t negx2[4];
  const float* x2b = x2h + b*NN + n0;
#pragma unroll
  for (int i = 0; i < 4; ++i) {
    float4_t v = *(const float4_t*)(x2b + i*16 + q*4);
    negx2[i] = {-v[0], -v[1], -v[2], -v[3]};
  }

  float rowmax[4][4];
#pragma unroll
  for (int i = 0; i < 4; ++i)
#pragma unroll
    for (int r = 0; r < 4; ++r) rowmax[i][r] = -3.0e38f;

  // ---- pointer-bumped streams (no per-iter address rebuild) ----
  const u16*  pB = ys + (size_t)((b << 6) + mt_start) * TILE_SHORTS
                   + (w*4)*512 + lane*8;
  const float* pY = y2h + b*NN + mt_start*128 + w*32 + l15;
  float*    colp = colpart + (size_t)((b << 7) | nt) * NN;
  unsigned* colu = colmax_u + b*NN;
  int coff = mt_start*128 + w*32 + q*16 + l15;     // valid where q < 2

  short8 bA[2][2], bB[2][2];
  float  yA[2],   yB[2];

  auto loadB = [&](short8 (&B)[2][2], float (&Y)[2]) {
    B[0][0] = *(const short8*)(pB);
    B[0][1] = *(const short8*)(pB + 512);
    B[1][0] = *(const short8*)(pB + 1024);
    B[1][1] = *(const short8*)(pB + 1536);
    Y[0] = pY[0];
    Y[1] = pY[16];
    pB += TILE_SHORTS;
    pY += 128;
  };

  auto compute = [&](const short8 (&B)[2][2], const float (&Y)[2]) {
    float cmax[2];
#pragma unroll
    for (int j = 0; j < 2; ++j) {
      // acc = xy - x2/2 (C carries exact fp32 -x2/2); j-sequential keeps
      // live accumulators at 4 x float4
      float4_t acc[4];
#pragma unroll
      for (int i = 0; i < 4; ++i)
        acc[i] = __builtin_amdgcn_mfma_f32_16x16x32_bf16(afr[i][0], B[j][0], negx2[i], 0, 0, 0);
#pragma unroll
      for (int i = 0; i < 4; ++i)
        acc[i] = __builtin_amdgcn_mfma_f32_16x16x32_bf16(afr[i][1], B[j][1], acc[i], 0, 0, 0);

      // col side: pure max over rows in-lane (max3-shaped tree)
      float m0 = fmaxf(fmaxf(acc[0][0], acc[0][1]), fmaxf(acc[0][2], acc[0][3]));
#pragma unroll
      for (int i = 1; i < 4; ++i)
        m0 = fmaxf(fmaxf(m0, fmaxf(acc[i][0], acc[i][1])),
                   fmaxf(acc[i][2], acc[i][3]));
      cmax[j] = m0;

      // row side: rowmax = max(acc - y2/2) = -min(d^2)/2
      const float y2j = Y[j];
#pragma unroll
      for (int i = 0; i < 4; ++i)
#pragma unroll
        for (int r = 0; r < 4; ++r)
          rowmax[i][r] = fmaxf(rowmax[i][r], acc[i][r] - y2j);
    }

    // col-max: combine q-groups (rows) via shuffles; wave-private, no barrier
#pragma unroll
    for (int j = 0; j < 2; ++j) {
      cmax[j] = fmaxf(cmax[j], __shfl_xor(cmax[j], 16));
      cmax[j] = fmaxf(cmax[j], __shfl_xor(cmax[j], 32));
    }
    float cv = (q & 1) ? cmax[1] : cmax[0];
    if (q < 2) {
      if (use_part) colp[coff] = cv;
      else          atomicMax(&colu[coff], enc_ord(cv));
    }
    coff += 128;
  };

  // tail-peeled 2x rotation: 32 loads / 32 computes, prefetch distance 1,
  // zero register copies
  loadB(bA, yA);
  for (int it = 0; it < 15; ++it) {
    loadB(bB, yB);
    compute(bA, yA);
    loadB(bA, yA);
    compute(bB, yB);
  }
  loadB(bB, yB);
  compute(bA, yA);
  compute(bB, yB);

  // ---- row side finalize: shfl over cols (l15), then 4-wave LDS combine ----
#pragma unroll
  for (int i = 0; i < 4; ++i)
#pragma unroll
    for (int r = 0; r < 4; ++r) {
      float v = rowmax[i][r];
      v = fmaxf(v, __shfl_xor(v, 1));
      v = fmaxf(v, __shfl_xor(v, 2));
      v = fmaxf(v, __shfl_xor(v, 4));
      v = fmaxf(v, __shfl_xor(v, 8));
      rowmax[i][r] = v;
    }
  if (l15 == 0) {
#pragma unroll
    for (int i = 0; i < 4; ++i)
#pragma unroll
      for (int r = 0; r < 4; ++r)
        rowbuf[w][i*16 + q*4 + r] = rowmax[i][r];
  }
  __syncthreads();
  if (tid < 64) {
    float v = fmaxf(fmaxf(rowbuf[0][tid], rowbuf[1][tid]),
                    fmaxf(rowbuf[2][tid], rowbuf[3][tid]));   // -min(d^2)/2
    if (use_part) rowpart[(size_t)bid * 64 + tid] = v;
    else          atomicMax(&rowmax_u[b*NN + n0 + tid], enc_ord(v));
  }
}

// ---------------------------------------------------------------------------
// K3: col combine over 128 nt + sqrt; row combine over 2 h + sqrt; block sum;
// atomicAdd scaled result into out.
// ---------------------------------------------------------------------------
__global__ __launch_bounds__(256) void reduce_kernel(
    const float* __restrict__ rowpart, const float* __restrict__ colpart,
    const unsigned* __restrict__ rowmax_u, const unsigned* __restrict__ colmax_u,
    const float* __restrict__ y2h, float* __restrict__ out,
    const int use_part)
{
  const int bid = blockIdx.x;          // 256
  const int tid = threadIdx.x;
  const int g = bid*256 + tid;         // 0..65535
  const int b = g >> 13, m = g & (NN - 1);

  float vc, vr;
  if (use_part) {
    vc = -3.0e38f;
#pragma unroll 8
    for (int nt = 0; nt < 128; ++nt)
      vc = fmaxf(vc, colpart[(size_t)((b << 7) | nt) * NN + m]);
    const int nt = m >> 6, r = m & 63;
    float r0 = rowpart[(size_t)((0 << 10) | (nt << 3) | b) * 64 + r];
    float r1 = rowpart[(size_t)((1 << 10) | (nt << 3) | b) * 64 + r];
    vr = fmaxf(r0, r1);
  } else {
    vc = dec_ord(colmax_u[g]);
    vr = dec_ord(rowmax_u[g]);
  }
  float s = sqrtf(fmaxf(2.f*(y2h[g] - vc), 0.f))   // nearest-x for this y
          + sqrtf(fmaxf(-2.f*vr, 0.f));            // nearest-y for this x

#pragma unroll
  for (int d = 1; d < 64; d <<= 1) s += __shfl_xor(s, d);
  __shared__ float wsum[4];
  if ((tid & 63) == 0) wsum[tid >> 6] = s;
  __syncthreads();
  if (tid == 0)
    atomicAdd(out, (wsum[0] + wsum[1] + wsum[2] + wsum[3]) * (1.0f / 65536.0f));
}

// ---------------------------------------------------------------------------
extern "C" void kernel_launch(void* const* d_in, const int* in_sizes, int n_in,
                              void* d_out, int out_size, void* d_ws, size_t ws_size,
                              hipStream_t stream) {
  const float* x = (const float*)d_in[0];
  const float* y = (const float*)d_in[1];
  float* out = (float*)d_out;

  char* p = (char*)d_ws;
  u16* xs = (u16*)p;            p += (size_t)512 * 16384;   // 8 MiB
  u16* ys = (u16*)p;            p += (size_t)512 * 16384;   // 8 MiB
  float* x2h = (float*)p;       p += (size_t)65536 * 4;
  float* y2h = (float*)p;       p += (size_t)65536 * 4;
  char* tail = p;
  // partial path: colpart 32 MiB (1024 slabs x 8192) + rowpart 512 KiB
  float* colpart = (float*)tail;
  float* rowpart = (float*)(tail + (size_t)1024 * 8192 * 4);
  // atomic fallback: two 256 KiB ordered-uint max buffers
  unsigned* colmax_u = (unsigned*)tail;
  unsigned* rowmax_u = (unsigned*)(tail + (size_t)65536 * 4);
  const size_t need_part = (size_t)(tail - (char*)d_ws) +
                           (size_t)1024 * 8192 * 4 + (size_t)2048 * 64 * 4;
  const int use_part = (ws_size >= need_part) ? 1 : 0;

  pre_kernel<<<dim3(1024), dim3(256), 0, stream>>>(x, y, xs, ys, x2h, y2h,
                                                   rowmax_u, colmax_u, out,
                                                   use_part);
  main_kernel<<<dim3(2048), dim3(256), 0, stream>>>(xs, ys, x2h, y2h,
                                                    rowpart, colpart,
                                                    rowmax_u, colmax_u,
                                                    use_part);
  reduce_kernel<<<dim3(256), dim3(256), 0, stream>>>(rowpart, colpart,
                                                     rowmax_u, colmax_u, y2h,
                                                     out, use_part);
}